// Round 14
// baseline (274.605 us; speedup 1.0000x reference)
//
#include <hip/hip_runtime.h>

#define NE 640000
#define NN 20000
#define SEI 200   // Ein stride (shorts): 192 + pad (400B/row)
#define SEH 136   // Eh stride: 128 + pad

typedef __attribute__((ext_vector_type(8))) short s16x8;
typedef __attribute__((ext_vector_type(4))) short s16x4;
typedef __attribute__((ext_vector_type(4))) float f32x4;

typedef const __attribute__((ext_vector_type(4))) float cf32x4;

// lgkmcnt-only barrier (no vmcnt drain); sched_barrier pins ordering (rule #18).
#define BARRIER_LGKM() do {                                   \
    asm volatile("s_waitcnt lgkmcnt(0)" ::: "memory");        \
    __builtin_amdgcn_s_barrier();                             \
    __builtin_amdgcn_sched_barrier(0);                        \
  } while (0)

__device__ __forceinline__ short f2bf(float f) {
  unsigned int u = __float_as_uint(f);
  u += 0x7fffu + ((u >> 16) & 1u);   // RNE
  return (short)(u >> 16);
}

__device__ __forceinline__ s16x8 cvt8(f32x4 a, f32x4 b) {
  s16x8 o;
  o[0]=f2bf(a[0]); o[1]=f2bf(a[1]); o[2]=f2bf(a[2]); o[3]=f2bf(a[3]);
  o[4]=f2bf(b[0]); o[5]=f2bf(b[1]); o[6]=f2bf(b[2]); o[7]=f2bf(b[3]);
  return o;
}

// One-time weight fragments via LDS (256 threads, 4 waves): coalesced
// row-major f32->bf16 copy, transposed per-lane u16 reads, W1 then W2
// reusing the same region. Needs smem >= 49152 B (W1).
__device__ __forceinline__ void load_wfrags_lds(const float* W1, const float* W2,
                                                const float* b1, const float* b2,
                                                short* smem, int t,
                                                int wv, int r, int g,
                                                s16x8 w1f[2][6], s16x8 w2f[4],
                                                f32x4 b1r[2], f32x4* b2r) {
  #pragma unroll
  for (int i = 0; i < 24; ++i) {            // W1: 6144 f32x4 -> 48KB bf16
    int idx4 = t + i * 256;
    f32x4 v = ((cf32x4*)W1)[idx4];
    s16x4 pk; pk[0]=f2bf(v[0]); pk[1]=f2bf(v[1]); pk[2]=f2bf(v[2]); pk[3]=f2bf(v[3]);
    *(s16x4*)&smem[idx4 * 4] = pk;
  }
  __syncthreads();
  #pragma unroll
  for (int nn = 0; nn < 2; ++nn) {
    const int h = (wv*2+nn)*16 + r;
    #pragma unroll
    for (int kk = 0; kk < 6; ++kk) {
      s16x8 wf;
      #pragma unroll
      for (int i = 0; i < 8; ++i) wf[i] = smem[(kk*32 + g*8 + i)*128 + h];
      w1f[nn][kk] = wf;
    }
    b1r[nn] = *(cf32x4*)(b1 + (wv*2+nn)*16 + g*4);
  }
  __syncthreads();
  #pragma unroll
  for (int i = 0; i < 8; ++i) {             // W2: 2048 f32x4 -> 16KB bf16
    int idx4 = t + i * 256;
    f32x4 v = ((cf32x4*)W2)[idx4];
    s16x4 pk; pk[0]=f2bf(v[0]); pk[1]=f2bf(v[1]); pk[2]=f2bf(v[2]); pk[3]=f2bf(v[3]);
    *(s16x4*)&smem[idx4 * 4] = pk;
  }
  __syncthreads();
  {
    const int h2 = wv*16 + r;
    #pragma unroll
    for (int kk = 0; kk < 4; ++kk) {
      s16x8 wf;
      #pragma unroll
      for (int i = 0; i < 8; ++i) wf[i] = smem[(kk*32 + g*8 + i)*64 + h2];
      w2f[kk] = wf;
    }
    *b2r = *(cf32x4*)(b2 + wv*16 + g*4);
  }
  __syncthreads();
}

// ---------------- CSR build ----------------

__global__ void count_kernel(const int* __restrict__ eidx, int* __restrict__ cursor) {
  const int4* d4 = (const int4*)(eidx + NE);
  int i = blockIdx.x * blockDim.x + threadIdx.x;
  if (i < NE / 4) {
    int4 d = d4[i];
    atomicAdd(&cursor[d.x], 1);
    atomicAdd(&cursor[d.y], 1);
    atomicAdd(&cursor[d.z], 1);
    atomicAdd(&cursor[d.w], 1);
  }
}

__global__ __launch_bounds__(1024)
void scan_kernel(int* __restrict__ cursor, int* __restrict__ offs) {
  __shared__ int cnt[20480];                 // 80KB
  __shared__ int part[1024];
  const int t = threadIdx.x;
  for (int i = t; i < 20480; i += 1024)
    cnt[i] = (i < NN) ? cursor[i] : 0;
  __syncthreads();
  const int lo = t * 20;
  int s = 0;
  #pragma unroll
  for (int k = 0; k < 20; ++k) s += cnt[lo + k];
  part[t] = s;
  __syncthreads();
  for (int d = 1; d < 1024; d <<= 1) {       // inclusive Hillis-Steele
    int u = (t >= d) ? part[t - d] : 0;
    __syncthreads();
    part[t] += u;
    __syncthreads();
  }
  int run = part[t] - s;                     // exclusive base
  #pragma unroll
  for (int k = 0; k < 20; ++k) {
    int c = cnt[lo + k];
    cnt[lo + k] = run;
    run += c;
  }
  __syncthreads();
  for (int i = t; i < NN; i += 1024) {
    int v = cnt[i];
    offs[i] = v;
    cursor[i] = v;
  }
  if (t == 1023) offs[NN] = NE;
}

__global__ void scatter_kernel(const int* __restrict__ eidx,
                               int* __restrict__ cursor, int* __restrict__ elist) {
  const int4* d4 = (const int4*)(eidx + NE);
  int i = blockIdx.x * blockDim.x + threadIdx.x;
  if (i < NE / 4) {
    int4 d = d4[i];
    const int e = i * 4;
    elist[atomicAdd(&cursor[d.x], 1)] = e;
    elist[atomicAdd(&cursor[d.y], 1)] = e + 1;
    elist[atomicAdd(&cursor[d.z], 1)] = e + 2;
    elist[atomicAdd(&cursor[d.w], 1)] = e + 3;
  }
}

// ---------------- fused edge model + aggregation ----------------
// Dest-sorted 64-edge tiles, contiguous range per block, 4 waves (wave wv:
// h-tiles {2wv,2wv+1} L1, d-tile wv L2). SINGLE Ein buffer (r8 phase order)
// + in-register shuffle segmented reduce (dests monotone in r) replace the
// double-buffered Ein and the Eout LDS round-trip -> smem 48KB -> 3 blocks/CU
// (12 waves, vs 8 at r12's 69.6KB) with 2 lgkm barriers/tile.
// LDS map (49152B): staging W1 [0,49152) then W2 [0,16384); compute
// Ein [0,25600) | Eh [25600,43008) | sDest0/1 [43008,43520) | sEid0/1 [43520,44032).
#define LOAD_ROWS(sv, dv, ee) do {                                        \
    cf32x4* ps_ = (cf32x4*)(x  + (size_t)(sv)*64 + p*16);                 \
    cf32x4* pd_ = (cf32x4*)(x  + (size_t)(dv)*64 + p*16);                 \
    cf32x4* pe_ = (cf32x4*)(ea + (size_t)(ee)*64 + p*16);                 \
    L[0]=ps_[0]; L[1]=ps_[1]; L[2]=ps_[2];  L[3]=ps_[3];                  \
    L[4]=pd_[0]; L[5]=pd_[1]; L[6]=pd_[2];  L[7]=pd_[3];                  \
    L[8]=pe_[0]; L[9]=pe_[1]; L[10]=pe_[2]; L[11]=pe_[3];                 \
  } while (0)

#define WRITE_EIN(buf) do {                                               \
    short* stg_ = (buf) + el*SEI + p*16;                                  \
    ((s16x8*)stg_)[0]       = cvt8(L[0], L[1]);                           \
    ((s16x8*)stg_)[1]       = cvt8(L[2], L[3]);                           \
    ((s16x8*)(stg_+64))[0]  = cvt8(L[4], L[5]);                           \
    ((s16x8*)(stg_+64))[1]  = cvt8(L[6], L[7]);                           \
    ((s16x8*)(stg_+128))[0] = cvt8(L[8], L[9]);                           \
    ((s16x8*)(stg_+128))[1] = cvt8(L[10], L[11]);                         \
  } while (0)

__global__ __launch_bounds__(256, 2)
void edge_kernel(const float* __restrict__ x, const int* __restrict__ eidx,
                 const float* __restrict__ ea, const int* __restrict__ elist,
                 const float* __restrict__ We1, const float* __restrict__ be1,
                 const float* __restrict__ We2, const float* __restrict__ be2,
                 float* __restrict__ edge_out, float* __restrict__ agg)
{
  __shared__ __align__(16) char smem[49152];
  short* sEin  = (short*)smem;
  short* sEh   = (short*)(smem + 25600);
  int* sDest0  = (int*)(smem + 43008);
  int* sDest1  = (int*)(smem + 43264);
  int* sEid0   = (int*)(smem + 43520);
  int* sEid1   = (int*)(smem + 43776);

  const int t = threadIdx.x;
  const int wv = t >> 6, lane = t & 63;
  const int r = lane & 15, g = lane >> 4;

  s16x8 w1f[2][6], w2f[4];
  f32x4 b1r[2], b2r;
  load_wfrags_lds(We1, We2, be1, be2, (short*)smem, t, wv, r, g,
                  w1f, w2f, b1r, &b2r);

  const int el = t >> 2, p = t & 3;
  const f32x4 zero = {0.f, 0.f, 0.f, 0.f};

  // contiguous range: 768 blocks over 10000 tiles (16 blocks get 14, rest 13)
  const int b = blockIdx.x;
  const int t0 = b * 13 + (b < 16 ? b : 16);
  const int t1 = t0 + (b < 16 ? 14 : 13);

  f32x4 L[12];
  int eW = 0, dW = 0;                        // ids of tile T+1 (stage-write)
  int eI = 0, sI = 0, dI = 0;                // ids of tile T+2 (row loads)
  int tile = t0;

  {                                          // prologue: tile t0 fully staged
    int e0 = elist[(tile << 6) + el];
    int s0 = eidx[e0], d0 = eidx[NE + e0];
    LOAD_ROWS(s0, d0, e0);
    WRITE_EIN(sEin);
    if (p == 0) { sDest0[el] = d0; sEid0[el] = e0; }
    if (tile + 1 < t1) {
      eW = elist[((tile + 1) << 6) + el];
      int sv = eidx[eW]; dW = eidx[NE + eW];
      LOAD_ROWS(sv, dW, eW);
    }
    if (tile + 2 < t1) {
      eI = elist[((tile + 2) << 6) + el];
      sI = eidx[eI]; dI = eidx[NE + eI];
    }
  }
  BARRIER_LGKM();

  int cur = 0;
  while (tile < t1) {
    const int* sDestC = cur ? sDest1 : sDest0;
    const int* sEidC  = cur ? sEid1  : sEid0;
    int* sDestN = cur ? sDest0 : sDest1;
    int* sEidN  = cur ? sEid0  : sEid1;
    const int tW = tile + 1, tI = tile + 2, tX = tile + 3;

    // ---- layer 1: 64 edges x 32 h per wave (reads Ein, writes Eh) ----
    f32x4 acc1[2][4];
    #pragma unroll
    for (int nn = 0; nn < 2; ++nn)
      #pragma unroll
      for (int j = 0; j < 4; ++j) acc1[nn][j] = zero;
    #pragma unroll
    for (int kk = 0; kk < 6; ++kk) {
      #pragma unroll
      for (int j = 0; j < 4; ++j) {
        s16x8 ef = *(const s16x8*)&sEin[(j*16 + r)*SEI + kk*32 + g*8];
        acc1[0][j] = __builtin_amdgcn_mfma_f32_16x16x32_bf16(w1f[0][kk], ef, acc1[0][j], 0, 0, 0);
        acc1[1][j] = __builtin_amdgcn_mfma_f32_16x16x32_bf16(w1f[1][kk], ef, acc1[1][j], 0, 0, 0);
      }
    }
    #pragma unroll
    for (int nn = 0; nn < 2; ++nn)
      #pragma unroll
      for (int j = 0; j < 4; ++j) {
        s16x4 pk;
        #pragma unroll
        for (int q = 0; q < 4; ++q) {
          float v = acc1[nn][j][q] + b1r[nn][q];
          pk[q] = f2bf(v > 0.f ? v : 0.f);
        }
        *(s16x4*)&sEh[(j*16 + r)*SEH + (wv*2+nn)*16 + g*4] = pk;
      }
    BARRIER_LGKM();                          // bar A: Eh visible; Ein consumed

    // ---- stage t+1 into the single Ein + issue t+2 loads + t+3 ids ----
    if (tW < t1) {
      WRITE_EIN(sEin);
      if (p == 0) { sDestN[el] = dW; sEidN[el] = eW; }
    }
    if (tI < t1) { LOAD_ROWS(sI, dI, eI); eW = eI; dW = dI; }
    if (tX < t1) {
      eI = elist[(tX << 6) + el];
      sI = eidx[eI]; dI = eidx[NE + eI];
    }

    // ---- layer 2 + scattered edge_out + in-register segmented reduce ----
    #pragma unroll
    for (int j = 0; j < 4; ++j) {
      f32x4 a2 = zero;
      #pragma unroll
      for (int kk = 0; kk < 4; ++kk) {
        s16x8 hf = *(const s16x8*)&sEh[(j*16 + r)*SEH + kk*32 + g*8];
        a2 = __builtin_amdgcn_mfma_f32_16x16x32_bf16(w2f[kk], hf, a2, 0, 0, 0);
      }
      a2 += b2r;
      const int eg = sEidC[j*16 + r];
      *(f32x4*)&edge_out[(size_t)eg*64 + wv*16 + g*4] = a2;

      // segmented prefix-sum over r (16-lane groups; dests monotone in r):
      // after 4 masked shfl_up steps, each segment-tail lane holds the
      // segment sum for its 4 columns; tails issue 4 scalar atomics.
      int d = sDestC[j*16 + r];
      f32x4 v = a2;
      #pragma unroll
      for (int off = 1; off < 16; off <<= 1) {
        int du = __shfl_up(d, off, 16);
        f32x4 u;
        #pragma unroll
        for (int q = 0; q < 4; ++q) u[q] = __shfl_up(v[q], off, 16);
        if (r >= off && du == d) v += u;
      }
      const bool tail = (r == 15) || (sDestC[j*16 + r + 1] != d);
      if (tail) {
        #pragma unroll
        for (int q = 0; q < 4; ++q)
          unsafeAtomicAdd(&agg[(size_t)d*64 + wv*16 + g*4 + q], v[q]);
      }
    }
    BARRIER_LGKM();                          // bar B: Ein(t+1) visible; Eh free
    cur ^= 1;
    tile = tW;
  }
}

// ---------------- node model (r12 structure, unchanged) ----------------
__global__ __launch_bounds__(256, 2)
void node_kernel(const float* __restrict__ x, const float* agg,
                 const float* __restrict__ f,
                 const float* __restrict__ Wn1, const float* __restrict__ bn1,
                 const float* __restrict__ Wn2, const float* __restrict__ bn2,
                 float* x_out)
{
  __shared__ __align__(16) char smem[49152];
  short* sEin = (short*)smem;
  short* sEh  = (short*)(smem + 25600);

  const int t = threadIdx.x;
  const int wv = t >> 6, lane = t & 63;
  const int r = lane & 15, g = lane >> 4;

  s16x8 w1f[2][6], w2f[4];
  f32x4 b1r[2], b2r;
  load_wfrags_lds(Wn1, Wn2, bn1, bn2, (short*)smem, t, wv, r, g,
                  w1f, w2f, b1r, &b2r);

  const int el = t >> 2, p = t & 3;
  const f32x4 zero = {0.f, 0.f, 0.f, 0.f};
  const int nT = (NN + 63) / 64;             // 313

  for (int tile = blockIdx.x; tile < nT; tile += (int)gridDim.x) {
    const int base = tile << 6;
    const int i = base + el;

    f32x4 L[12];
    if (i < NN) {
      cf32x4* ps_ = (cf32x4*)(x   + (size_t)i*64 + p*16);
      cf32x4* pa_ = (cf32x4*)(agg + (size_t)i*64 + p*16);
      cf32x4* pf_ = (cf32x4*)(f   + (size_t)i*64 + p*16);
      L[0]=ps_[0]; L[1]=ps_[1]; L[2]=ps_[2];  L[3]=ps_[3];
      L[4]=pa_[0]; L[5]=pa_[1]; L[6]=pa_[2];  L[7]=pa_[3];
      L[8]=pf_[0]; L[9]=pf_[1]; L[10]=pf_[2]; L[11]=pf_[3];
    } else {
      #pragma unroll
      for (int q = 0; q < 12; ++q) L[q] = zero;
    }
    WRITE_EIN(sEin);
    __syncthreads();

    f32x4 acc1[2][4];
    #pragma unroll
    for (int nn = 0; nn < 2; ++nn)
      #pragma unroll
      for (int j = 0; j < 4; ++j) acc1[nn][j] = zero;
    #pragma unroll
    for (int kk = 0; kk < 6; ++kk) {
      #pragma unroll
      for (int j = 0; j < 4; ++j) {
        s16x8 ef = *(const s16x8*)&sEin[(j*16 + r)*SEI + kk*32 + g*8];
        acc1[0][j] = __builtin_amdgcn_mfma_f32_16x16x32_bf16(w1f[0][kk], ef, acc1[0][j], 0, 0, 0);
        acc1[1][j] = __builtin_amdgcn_mfma_f32_16x16x32_bf16(w1f[1][kk], ef, acc1[1][j], 0, 0, 0);
      }
    }
    #pragma unroll
    for (int nn = 0; nn < 2; ++nn)
      #pragma unroll
      for (int j = 0; j < 4; ++j) {
        s16x4 pk;
        #pragma unroll
        for (int q = 0; q < 4; ++q) {
          float v = acc1[nn][j][q] + b1r[nn][q];
          pk[q] = f2bf(v > 0.f ? v : 0.f);
        }
        *(s16x4*)&sEh[(j*16 + r)*SEH + (wv*2+nn)*16 + g*4] = pk;
      }
    __syncthreads();

    #pragma unroll
    for (int j = 0; j < 4; ++j) {
      f32x4 a2 = zero;
      #pragma unroll
      for (int kk = 0; kk < 4; ++kk) {
        s16x8 hf = *(const s16x8*)&sEh[(j*16 + r)*SEH + kk*32 + g*8];
        a2 = __builtin_amdgcn_mfma_f32_16x16x32_bf16(w2f[kk], hf, a2, 0, 0, 0);
      }
      const int row = base + j*16 + r;
      if (row < NN) {
        f32x4 v = a2 + b2r;
        *(f32x4*)&x_out[(size_t)row*64 + wv*16 + g*4] = v;
      }
    }
  }
}

extern "C" void kernel_launch(void* const* d_in, const int* in_sizes, int n_in,
                              void* d_out, int out_size, void* d_ws, size_t ws_size,
                              hipStream_t stream) {
  const float* x   = (const float*)d_in[0];
  const int*   ei  = (const int*)d_in[1];
  const float* ea  = (const float*)d_in[2];
  const float* f   = (const float*)d_in[3];
  const float* We1 = (const float*)d_in[4];
  const float* be1 = (const float*)d_in[5];
  const float* We2 = (const float*)d_in[6];
  const float* be2 = (const float*)d_in[7];
  const float* Wn1 = (const float*)d_in[8];
  const float* bn1 = (const float*)d_in[9];
  const float* Wn2 = (const float*)d_in[10];
  const float* bn2 = (const float*)d_in[11];

  float* x_out    = (float*)d_out;                    // [20000*64] — doubles as agg
  float* edge_out = x_out + (size_t)NN * 64;          // [640000*64]

  // CSR scratch in d_ws: cursor[NN] | offs[NN+1] | elist[NE]  (~2.8 MB)
  int* cursor = (int*)d_ws;
  int* offs   = cursor + NN;
  int* elist  = offs + NN + 8;

  hipMemsetAsync(x_out, 0, (size_t)NN * 64 * sizeof(float), stream);  // agg = 0
  hipMemsetAsync(cursor, 0, NN * sizeof(int), stream);
  count_kernel<<<625, 256, 0, stream>>>(ei, cursor);
  scan_kernel<<<1, 1024, 0, stream>>>(cursor, offs);
  scatter_kernel<<<625, 256, 0, stream>>>(ei, cursor, elist);
  edge_kernel<<<768, 256, 0, stream>>>(x, ei, ea, elist, We1, be1, We2, be2,
                                       edge_out, x_out);
  node_kernel<<<105, 256, 0, stream>>>(x, x_out, f, Wn1, bn1, Wn2, bn2, x_out);
}

// Round 15
// 223.362 us; speedup vs baseline: 1.2294x; 1.2294x over previous
//
#include <hip/hip_runtime.h>

#define NE 640000
#define NN 20000
#define SEI 200   // Ein stride (shorts): 192 + pad
#define SEH 136   // Eh stride: 128 + pad (bf16 phase)
#define SEO 68    // Eout stride (f32): 64 + pad; lives in the Ecur Ein region

typedef __attribute__((ext_vector_type(8))) short s16x8;
typedef __attribute__((ext_vector_type(4))) short s16x4;
typedef __attribute__((ext_vector_type(4))) float f32x4;

typedef const __attribute__((ext_vector_type(4))) float cf32x4;

__device__ __forceinline__ short f2bf(float f) {
  unsigned int u = __float_as_uint(f);
  u += 0x7fffu + ((u >> 16) & 1u);   // RNE
  return (short)(u >> 16);
}

__device__ __forceinline__ s16x8 cvt8(f32x4 a, f32x4 b) {
  s16x8 o;
  o[0]=f2bf(a[0]); o[1]=f2bf(a[1]); o[2]=f2bf(a[2]); o[3]=f2bf(a[3]);
  o[4]=f2bf(b[0]); o[5]=f2bf(b[1]); o[6]=f2bf(b[2]); o[7]=f2bf(b[3]);
  return o;
}

// One-time weight fragments via LDS: coalesced row-major f32->bf16 copy,
// transposed per-lane u16 reads, W1 then W2 reusing the same region.
__device__ __forceinline__ void load_wfrags_lds(const float* W1, const float* W2,
                                                const float* b1, const float* b2,
                                                short* smem, int t,
                                                int wv, int r, int g,
                                                s16x8 w1f[2][6], s16x8 w2f[4],
                                                f32x4 b1r[2], f32x4* b2r) {
  #pragma unroll
  for (int i = 0; i < 24; ++i) {            // W1: 6144 f32x4 -> 48KB bf16
    int idx4 = t + i * 256;
    f32x4 v = ((cf32x4*)W1)[idx4];
    s16x4 pk; pk[0]=f2bf(v[0]); pk[1]=f2bf(v[1]); pk[2]=f2bf(v[2]); pk[3]=f2bf(v[3]);
    *(s16x4*)&smem[idx4 * 4] = pk;
  }
  __syncthreads();
  #pragma unroll
  for (int nn = 0; nn < 2; ++nn) {
    const int h = (wv*2+nn)*16 + r;
    #pragma unroll
    for (int kk = 0; kk < 6; ++kk) {
      s16x8 wf;
      #pragma unroll
      for (int i = 0; i < 8; ++i) wf[i] = smem[(kk*32 + g*8 + i)*128 + h];
      w1f[nn][kk] = wf;
    }
    b1r[nn] = *(cf32x4*)(b1 + (wv*2+nn)*16 + g*4);
  }
  __syncthreads();
  #pragma unroll
  for (int i = 0; i < 8; ++i) {             // W2: 2048 f32x4 -> 16KB bf16
    int idx4 = t + i * 256;
    f32x4 v = ((cf32x4*)W2)[idx4];
    s16x4 pk; pk[0]=f2bf(v[0]); pk[1]=f2bf(v[1]); pk[2]=f2bf(v[2]); pk[3]=f2bf(v[3]);
    *(s16x4*)&smem[idx4 * 4] = pk;
  }
  __syncthreads();
  {
    const int h2 = wv*16 + r;
    #pragma unroll
    for (int kk = 0; kk < 4; ++kk) {
      s16x8 wf;
      #pragma unroll
      for (int i = 0; i < 8; ++i) wf[i] = smem[(kk*32 + g*8 + i)*64 + h2];
      w2f[kk] = wf;
    }
    *b2r = *(cf32x4*)(b2 + wv*16 + g*4);
  }
  __syncthreads();
}

// ---------------- CSR build ----------------

// int4 dest reads + folds the agg (=x_out) zeroing in (saves one memset
// dispatch; ordering vs edge_kernel's atomics is guaranteed by the
// count->scan->scatter->edge kernel-boundary chain).
__global__ void count_kernel(const int* __restrict__ eidx, int* __restrict__ cursor,
                             float* __restrict__ agg) {
  const int4* d4 = (const int4*)(eidx + NE);
  int i = blockIdx.x * blockDim.x + threadIdx.x;
  if (i < NE / 4) {
    int4 d = d4[i];
    atomicAdd(&cursor[d.x], 1);
    atomicAdd(&cursor[d.y], 1);
    atomicAdd(&cursor[d.z], 1);
    atomicAdd(&cursor[d.w], 1);
  }
  if (i < NN * 64 / 8) {                     // zero agg: 8 floats/thread
    f32x4 z = {0.f, 0.f, 0.f, 0.f};
    ((f32x4*)agg)[i*2]   = z;
    ((f32x4*)agg)[i*2+1] = z;
  }
}

// Single block; counts staged via LDS so all global traffic is coalesced.
__global__ __launch_bounds__(1024)
void scan_kernel(int* __restrict__ cursor, int* __restrict__ offs) {
  __shared__ int cnt[20480];                 // 80KB
  __shared__ int part[1024];
  const int t = threadIdx.x;
  for (int i = t; i < 20480; i += 1024)
    cnt[i] = (i < NN) ? cursor[i] : 0;
  __syncthreads();
  const int lo = t * 20;
  int s = 0;
  #pragma unroll
  for (int k = 0; k < 20; ++k) s += cnt[lo + k];
  part[t] = s;
  __syncthreads();
  for (int d = 1; d < 1024; d <<= 1) {       // inclusive Hillis-Steele
    int u = (t >= d) ? part[t - d] : 0;
    __syncthreads();
    part[t] += u;
    __syncthreads();
  }
  int run = part[t] - s;                     // exclusive base
  #pragma unroll
  for (int k = 0; k < 20; ++k) {
    int c = cnt[lo + k];
    cnt[lo + k] = run;
    run += c;
  }
  __syncthreads();
  for (int i = t; i < NN; i += 1024) {
    int v = cnt[i];
    offs[i] = v;
    cursor[i] = v;
  }
  if (t == 1023) offs[NN] = NE;
}

__global__ void scatter_kernel(const int* __restrict__ eidx,
                               int* __restrict__ cursor, int* __restrict__ elist) {
  const int4* d4 = (const int4*)(eidx + NE);
  int i = blockIdx.x * blockDim.x + threadIdx.x;
  if (i < NE / 4) {
    int4 d = d4[i];
    const int e = i * 4;
    elist[atomicAdd(&cursor[d.x], 1)] = e;
    elist[atomicAdd(&cursor[d.y], 1)] = e + 1;
    elist[atomicAdd(&cursor[d.z], 1)] = e + 2;
    elist[atomicAdd(&cursor[d.w], 1)] = e + 3;
  }
}

// ---------------- fused edge model + aggregation (r11 structure) ----------------
// Dest-sorted (elist) 64-edge tiles, stride-gridDim loop; 4 waves (wave w:
// h-tiles {2w,2w+1} L1, d-tile w L2), double-buffered Ein, 3-stage prefetch.
// After layer2: scattered edge_out stores; f32 Eout transposes through the
// *Ecur* Ein region (free after bar A; reuse fenced by bar D) -> 3
// __syncthreads/tile. Per-wave segmented reduce over 16 sorted edges ->
// coalesced 256B row unsafeAtomicAdds (~1-2/wave-chunk).
// LDS map (69632B): staging W1 [0,49152) then W2 [0,16384); compute
// Ein0 [0,25600) | Ein1 [25600,51200) | Eh [51200,68608) |
// sDest0/1 [68608,69120) | sEid0/1 [69120,69632). Eout = Ecur's region.
#define LOAD_ROWS(sv, dv, ee) do {                                        \
    cf32x4* ps_ = (cf32x4*)(x  + (size_t)(sv)*64 + p*16);                 \
    cf32x4* pd_ = (cf32x4*)(x  + (size_t)(dv)*64 + p*16);                 \
    cf32x4* pe_ = (cf32x4*)(ea + (size_t)(ee)*64 + p*16);                 \
    L[0]=ps_[0]; L[1]=ps_[1]; L[2]=ps_[2];  L[3]=ps_[3];                  \
    L[4]=pd_[0]; L[5]=pd_[1]; L[6]=pd_[2];  L[7]=pd_[3];                  \
    L[8]=pe_[0]; L[9]=pe_[1]; L[10]=pe_[2]; L[11]=pe_[3];                 \
  } while (0)

#define WRITE_EIN(buf) do {                                               \
    short* stg_ = (buf) + el*SEI + p*16;                                  \
    ((s16x8*)stg_)[0]       = cvt8(L[0], L[1]);                           \
    ((s16x8*)stg_)[1]       = cvt8(L[2], L[3]);                           \
    ((s16x8*)(stg_+64))[0]  = cvt8(L[4], L[5]);                           \
    ((s16x8*)(stg_+64))[1]  = cvt8(L[6], L[7]);                           \
    ((s16x8*)(stg_+128))[0] = cvt8(L[8], L[9]);                           \
    ((s16x8*)(stg_+128))[1] = cvt8(L[10], L[11]);                         \
  } while (0)

__global__ __launch_bounds__(256, 2)
void edge_kernel(const float* __restrict__ x, const int* __restrict__ eidx,
                 const float* __restrict__ ea, const int* __restrict__ elist,
                 const float* __restrict__ We1, const float* __restrict__ be1,
                 const float* __restrict__ We2, const float* __restrict__ be2,
                 float* __restrict__ edge_out, float* __restrict__ agg)
{
  __shared__ __align__(16) char smem[69632];
  short* sEin0 = (short*)smem;
  short* sEin1 = (short*)(smem + 25600);
  short* sEh   = (short*)(smem + 51200);
  int* sDest0  = (int*)(smem + 68608);
  int* sDest1  = (int*)(smem + 68864);
  int* sEid0   = (int*)(smem + 69120);
  int* sEid1   = (int*)(smem + 69376);

  const int t = threadIdx.x;
  const int wv = t >> 6, lane = t & 63;
  const int r = lane & 15, g = lane >> 4;

  s16x8 w1f[2][6], w2f[4];
  f32x4 b1r[2], b2r;
  load_wfrags_lds(We1, We2, be1, be2, (short*)smem, t, wv, r, g,
                  w1f, w2f, b1r, &b2r);

  const int el = t >> 2, p = t & 3;
  const int nT = NE / 64;                    // 10000
  const int S = (int)gridDim.x;
  const f32x4 zero = {0.f, 0.f, 0.f, 0.f};

  f32x4 L[12];
  int eW = 0, dW = 0;                        // ids of tile T+1 (stage-write)
  int eI = 0, sI = 0, dI = 0;                // ids of tile T+2 (row loads)
  int tile = blockIdx.x;

  if (tile < nT) {                           // prologue: tile T0 fully staged
    int e0 = elist[(tile << 6) + el];
    int s0 = eidx[e0], d0 = eidx[NE + e0];
    LOAD_ROWS(s0, d0, e0);
    WRITE_EIN(sEin0);
    if (p == 0) { sDest0[el] = d0; sEid0[el] = e0; }
    const int t1 = tile + S;
    if (t1 < nT) {
      eW = elist[(t1 << 6) + el];
      int sv = eidx[eW]; dW = eidx[NE + eW];
      LOAD_ROWS(sv, dW, eW);
    }
    const int t2 = tile + 2 * S;
    if (t2 < nT) {
      eI = elist[(t2 << 6) + el];
      sI = eidx[eI]; dI = eidx[NE + eI];
    }
  }
  __syncthreads();

  int cur = 0;
  while (tile < nT) {
    const short* Ecur = cur ? sEin1 : sEin0;
    short* Enxt = cur ? sEin0 : sEin1;
    float* EoutC = (float*)(cur ? (smem + 25600) : smem);
    const int* sDestC = cur ? sDest1 : sDest0;
    const int* sEidC  = cur ? sEid1  : sEid0;
    int* sDestN = cur ? sDest0 : sDest1;
    int* sEidN  = cur ? sEid0  : sEid1;

    const int tW = tile + S, tI = tile + 2 * S, tX = tile + 3 * S;
    if (tW < nT) {                           // stage T+1 (regs from last iter)
      WRITE_EIN(Enxt);
      if (p == 0) { sDestN[el] = dW; sEidN[el] = eW; }
    }
    if (tI < nT) { LOAD_ROWS(sI, dI, eI); eW = eI; dW = dI; }
    if (tX < nT) {
      eI = elist[(tX << 6) + el];
      sI = eidx[eI]; dI = eidx[NE + eI];
    }

    // ---- layer 1: 64 edges x 32 h per wave ----
    f32x4 acc1[2][4];
    #pragma unroll
    for (int nn = 0; nn < 2; ++nn)
      #pragma unroll
      for (int j = 0; j < 4; ++j) acc1[nn][j] = zero;
    #pragma unroll
    for (int kk = 0; kk < 6; ++kk) {
      #pragma unroll
      for (int j = 0; j < 4; ++j) {
        s16x8 ef = *(const s16x8*)&Ecur[(j*16 + r)*SEI + kk*32 + g*8];
        acc1[0][j] = __builtin_amdgcn_mfma_f32_16x16x32_bf16(w1f[0][kk], ef, acc1[0][j], 0, 0, 0);
        acc1[1][j] = __builtin_amdgcn_mfma_f32_16x16x32_bf16(w1f[1][kk], ef, acc1[1][j], 0, 0, 0);
      }
    }
    #pragma unroll
    for (int nn = 0; nn < 2; ++nn)
      #pragma unroll
      for (int j = 0; j < 4; ++j) {
        s16x4 pk;
        #pragma unroll
        for (int q = 0; q < 4; ++q) {
          float v = acc1[nn][j][q] + b1r[nn][q];
          pk[q] = f2bf(v > 0.f ? v : 0.f);
        }
        *(s16x4*)&sEh[(j*16 + r)*SEH + (wv*2+nn)*16 + g*4] = pk;
      }
    __syncthreads();                         // bar A: Eh ready, Ein reads done

    // ---- layer 2 + scattered edge_out store + Eout into Ecur region ----
    #pragma unroll
    for (int j = 0; j < 4; ++j) {
      f32x4 a2 = zero;
      #pragma unroll
      for (int kk = 0; kk < 4; ++kk) {
        s16x8 hf = *(const s16x8*)&sEh[(j*16 + r)*SEH + kk*32 + g*8];
        a2 = __builtin_amdgcn_mfma_f32_16x16x32_bf16(w2f[kk], hf, a2, 0, 0, 0);
      }
      a2 += b2r;
      const int eg = sEidC[j*16 + r];
      *(f32x4*)&edge_out[(size_t)eg*64 + wv*16 + g*4] = a2;
      *(f32x4*)&EoutC[(j*16 + r)*SEO + wv*16 + g*4] = a2;
    }
    __syncthreads();                         // bar C: Eout complete

    // ---- segmented reduce: wave wv owns sorted edges wv*16..+15 ----
    {
      const int row0 = wv * 16;
      float acc = EoutC[row0*SEO + lane];
      int dcur = sDestC[row0];
      #pragma unroll
      for (int k = 1; k < 16; ++k) {
        const int dn = sDestC[row0 + k];     // wave-uniform
        const float v = EoutC[(row0 + k)*SEO + lane];
        if (dn != dcur) {
          unsafeAtomicAdd(&agg[(size_t)dcur*64 + lane], acc);
          acc = v; dcur = dn;
        } else {
          acc += v;
        }
      }
      unsafeAtomicAdd(&agg[(size_t)dcur*64 + lane], acc);
    }
    __syncthreads();                         // bar D: Eout consumed
    cur ^= 1;
    tile = tW;
  }
}

// ---------------- node model ----------------
// Grid-stride over 64-node tiles (105 blocks x ~3 tiles). agg aliases x_out:
// each tile's rows are read then overwritten exclusively by the owning block.
__global__ __launch_bounds__(256, 2)
void node_kernel(const float* __restrict__ x, const float* agg,
                 const float* __restrict__ f,
                 const float* __restrict__ Wn1, const float* __restrict__ bn1,
                 const float* __restrict__ Wn2, const float* __restrict__ bn2,
                 float* x_out)
{
  __shared__ __align__(16) char smem[49152];
  short* sEin = (short*)smem;
  short* sEh  = (short*)(smem + 25600);

  const int t = threadIdx.x;
  const int wv = t >> 6, lane = t & 63;
  const int r = lane & 15, g = lane >> 4;

  s16x8 w1f[2][6], w2f[4];
  f32x4 b1r[2], b2r;
  load_wfrags_lds(Wn1, Wn2, bn1, bn2, (short*)smem, t, wv, r, g,
                  w1f, w2f, b1r, &b2r);

  const int el = t >> 2, p = t & 3;
  const f32x4 zero = {0.f, 0.f, 0.f, 0.f};
  const int nT = (NN + 63) / 64;             // 313

  for (int tile = blockIdx.x; tile < nT; tile += (int)gridDim.x) {
    const int base = tile << 6;
    const int i = base + el;

    f32x4 L[12];
    if (i < NN) {
      cf32x4* ps_ = (cf32x4*)(x   + (size_t)i*64 + p*16);
      cf32x4* pa_ = (cf32x4*)(agg + (size_t)i*64 + p*16);
      cf32x4* pf_ = (cf32x4*)(f   + (size_t)i*64 + p*16);
      L[0]=ps_[0]; L[1]=ps_[1]; L[2]=ps_[2];  L[3]=ps_[3];
      L[4]=pa_[0]; L[5]=pa_[1]; L[6]=pa_[2];  L[7]=pa_[3];
      L[8]=pf_[0]; L[9]=pf_[1]; L[10]=pf_[2]; L[11]=pf_[3];
    } else {
      #pragma unroll
      for (int q = 0; q < 12; ++q) L[q] = zero;
    }
    WRITE_EIN(sEin);
    __syncthreads();

    f32x4 acc1[2][4];
    #pragma unroll
    for (int nn = 0; nn < 2; ++nn)
      #pragma unroll
      for (int j = 0; j < 4; ++j) acc1[nn][j] = zero;
    #pragma unroll
    for (int kk = 0; kk < 6; ++kk) {
      #pragma unroll
      for (int j = 0; j < 4; ++j) {
        s16x8 ef = *(const s16x8*)&sEin[(j*16 + r)*SEI + kk*32 + g*8];
        acc1[0][j] = __builtin_amdgcn_mfma_f32_16x16x32_bf16(w1f[0][kk], ef, acc1[0][j], 0, 0, 0);
        acc1[1][j] = __builtin_amdgcn_mfma_f32_16x16x32_bf16(w1f[1][kk], ef, acc1[1][j], 0, 0, 0);
      }
    }
    #pragma unroll
    for (int nn = 0; nn < 2; ++nn)
      #pragma unroll
      for (int j = 0; j < 4; ++j) {
        s16x4 pk;
        #pragma unroll
        for (int q = 0; q < 4; ++q) {
          float v = acc1[nn][j][q] + b1r[nn][q];
          pk[q] = f2bf(v > 0.f ? v : 0.f);
        }
        *(s16x4*)&sEh[(j*16 + r)*SEH + (wv*2+nn)*16 + g*4] = pk;
      }
    __syncthreads();

    #pragma unroll
    for (int j = 0; j < 4; ++j) {
      f32x4 a2 = zero;
      #pragma unroll
      for (int kk = 0; kk < 4; ++kk) {
        s16x8 hf = *(const s16x8*)&sEh[(j*16 + r)*SEH + kk*32 + g*8];
        a2 = __builtin_amdgcn_mfma_f32_16x16x32_bf16(w2f[kk], hf, a2, 0, 0, 0);
      }
      const int row = base + j*16 + r;
      if (row < NN) {
        f32x4 v = a2 + b2r;
        *(f32x4*)&x_out[(size_t)row*64 + wv*16 + g*4] = v;
      }
    }
  }
}

extern "C" void kernel_launch(void* const* d_in, const int* in_sizes, int n_in,
                              void* d_out, int out_size, void* d_ws, size_t ws_size,
                              hipStream_t stream) {
  const float* x   = (const float*)d_in[0];
  const int*   ei  = (const int*)d_in[1];
  const float* ea  = (const float*)d_in[2];
  const float* f   = (const float*)d_in[3];
  const float* We1 = (const float*)d_in[4];
  const float* be1 = (const float*)d_in[5];
  const float* We2 = (const float*)d_in[6];
  const float* be2 = (const float*)d_in[7];
  const float* Wn1 = (const float*)d_in[8];
  const float* bn1 = (const float*)d_in[9];
  const float* Wn2 = (const float*)d_in[10];
  const float* bn2 = (const float*)d_in[11];

  float* x_out    = (float*)d_out;                    // [20000*64] — doubles as agg
  float* edge_out = x_out + (size_t)NN * 64;          // [640000*64]

  // CSR scratch in d_ws: cursor[NN] | offs[NN+1] | elist[NE]  (~2.8 MB)
  int* cursor = (int*)d_ws;
  int* offs   = cursor + NN;
  int* elist  = offs + NN + 8;

  hipMemsetAsync(cursor, 0, NN * sizeof(int), stream);
  count_kernel<<<625, 256, 0, stream>>>(ei, cursor, x_out);  // also zeros agg
  scan_kernel<<<1, 1024, 0, stream>>>(cursor, offs);
  scatter_kernel<<<625, 256, 0, stream>>>(ei, cursor, elist);
  edge_kernel<<<512, 256, 0, stream>>>(x, ei, ea, elist, We1, be1, We2, be2,
                                       edge_out, x_out);
  node_kernel<<<105, 256, 0, stream>>>(x, x_out, f, Wn1, bn1, Wn2, bn2, x_out);
}

// Round 16
// 223.314 us; speedup vs baseline: 1.2297x; 1.0002x over previous
//
#include <hip/hip_runtime.h>

#define NE 640000
#define NN 20000
#define SEI 200   // Ein stride (shorts): 192 + pad
#define SEH 136   // Eh stride: 128 + pad (bf16 phase)
#define SEO 68    // Eout stride (f32): 64 + pad; lives in the Ecur Ein region

typedef __attribute__((ext_vector_type(8))) short s16x8;
typedef __attribute__((ext_vector_type(4))) short s16x4;
typedef __attribute__((ext_vector_type(4))) float f32x4;

typedef const __attribute__((ext_vector_type(4))) float cf32x4;

__device__ __forceinline__ short f2bf(float f) {
  unsigned int u = __float_as_uint(f);
  u += 0x7fffu + ((u >> 16) & 1u);   // RNE
  return (short)(u >> 16);
}

__device__ __forceinline__ s16x8 cvt8(f32x4 a, f32x4 b) {
  s16x8 o;
  o[0]=f2bf(a[0]); o[1]=f2bf(a[1]); o[2]=f2bf(a[2]); o[3]=f2bf(a[3]);
  o[4]=f2bf(b[0]); o[5]=f2bf(b[1]); o[6]=f2bf(b[2]); o[7]=f2bf(b[3]);
  return o;
}

// One-time weight fragments via LDS: coalesced row-major f32->bf16 copy,
// transposed per-lane u16 reads, W1 then W2 reusing the same region.
__device__ __forceinline__ void load_wfrags_lds(const float* W1, const float* W2,
                                                const float* b1, const float* b2,
                                                short* smem, int t,
                                                int wv, int r, int g,
                                                s16x8 w1f[2][6], s16x8 w2f[4],
                                                f32x4 b1r[2], f32x4* b2r) {
  #pragma unroll
  for (int i = 0; i < 24; ++i) {            // W1: 6144 f32x4 -> 48KB bf16
    int idx4 = t + i * 256;
    f32x4 v = ((cf32x4*)W1)[idx4];
    s16x4 pk; pk[0]=f2bf(v[0]); pk[1]=f2bf(v[1]); pk[2]=f2bf(v[2]); pk[3]=f2bf(v[3]);
    *(s16x4*)&smem[idx4 * 4] = pk;
  }
  __syncthreads();
  #pragma unroll
  for (int nn = 0; nn < 2; ++nn) {
    const int h = (wv*2+nn)*16 + r;
    #pragma unroll
    for (int kk = 0; kk < 6; ++kk) {
      s16x8 wf;
      #pragma unroll
      for (int i = 0; i < 8; ++i) wf[i] = smem[(kk*32 + g*8 + i)*128 + h];
      w1f[nn][kk] = wf;
    }
    b1r[nn] = *(cf32x4*)(b1 + (wv*2+nn)*16 + g*4);
  }
  __syncthreads();
  #pragma unroll
  for (int i = 0; i < 8; ++i) {             // W2: 2048 f32x4 -> 16KB bf16
    int idx4 = t + i * 256;
    f32x4 v = ((cf32x4*)W2)[idx4];
    s16x4 pk; pk[0]=f2bf(v[0]); pk[1]=f2bf(v[1]); pk[2]=f2bf(v[2]); pk[3]=f2bf(v[3]);
    *(s16x4*)&smem[idx4 * 4] = pk;
  }
  __syncthreads();
  {
    const int h2 = wv*16 + r;
    #pragma unroll
    for (int kk = 0; kk < 4; ++kk) {
      s16x8 wf;
      #pragma unroll
      for (int i = 0; i < 8; ++i) wf[i] = smem[(kk*32 + g*8 + i)*64 + h2];
      w2f[kk] = wf;
    }
    *b2r = *(cf32x4*)(b2 + wv*16 + g*4);
  }
  __syncthreads();
}

// ---------------- CSR build ----------------

// int4 dest reads + folds the agg (=x_out) zeroing in.
__global__ void count_kernel(const int* __restrict__ eidx, int* __restrict__ cursor,
                             float* __restrict__ agg) {
  const int4* d4 = (const int4*)(eidx + NE);
  int i = blockIdx.x * blockDim.x + threadIdx.x;
  if (i < NE / 4) {
    int4 d = d4[i];
    atomicAdd(&cursor[d.x], 1);
    atomicAdd(&cursor[d.y], 1);
    atomicAdd(&cursor[d.z], 1);
    atomicAdd(&cursor[d.w], 1);
  }
  if (i < NN * 64 / 8) {                     // zero agg: 8 floats/thread
    f32x4 z = {0.f, 0.f, 0.f, 0.f};
    ((f32x4*)agg)[i*2]   = z;
    ((f32x4*)agg)[i*2+1] = z;
  }
}

// Single block; counts staged via LDS so all global traffic is coalesced.
__global__ __launch_bounds__(1024)
void scan_kernel(int* __restrict__ cursor, int* __restrict__ offs) {
  __shared__ int cnt[20480];                 // 80KB
  __shared__ int part[1024];
  const int t = threadIdx.x;
  for (int i = t; i < 20480; i += 1024)
    cnt[i] = (i < NN) ? cursor[i] : 0;
  __syncthreads();
  const int lo = t * 20;
  int s = 0;
  #pragma unroll
  for (int k = 0; k < 20; ++k) s += cnt[lo + k];
  part[t] = s;
  __syncthreads();
  for (int d = 1; d < 1024; d <<= 1) {       // inclusive Hillis-Steele
    int u = (t >= d) ? part[t - d] : 0;
    __syncthreads();
    part[t] += u;
    __syncthreads();
  }
  int run = part[t] - s;                     // exclusive base
  #pragma unroll
  for (int k = 0; k < 20; ++k) {
    int c = cnt[lo + k];
    cnt[lo + k] = run;
    run += c;
  }
  __syncthreads();
  for (int i = t; i < NN; i += 1024) {
    int v = cnt[i];
    offs[i] = v;
    cursor[i] = v;
  }
  if (t == 1023) offs[NN] = NE;
}

__global__ void scatter_kernel(const int* __restrict__ eidx,
                               int* __restrict__ cursor, int* __restrict__ elist) {
  const int4* d4 = (const int4*)(eidx + NE);
  int i = blockIdx.x * blockDim.x + threadIdx.x;
  if (i < NE / 4) {
    int4 d = d4[i];
    const int e = i * 4;
    elist[atomicAdd(&cursor[d.x], 1)] = e;
    elist[atomicAdd(&cursor[d.y], 1)] = e + 1;
    elist[atomicAdd(&cursor[d.z], 1)] = e + 2;
    elist[atomicAdd(&cursor[d.w], 1)] = e + 3;
  }
}

// ---------------- fused edge model + aggregation (converged structure) ----------------
// Dest-sorted (elist) 64-edge tiles, stride-gridDim loop; 4 waves (wave w:
// h-tiles {2w,2w+1} L1, d-tile w L2), double-buffered Ein, 3-stage prefetch.
// After layer2: scattered edge_out stores; f32 Eout transposes through the
// *Ecur* Ein region; per-wave segmented reduce -> coalesced 256B row atomics.
// LDS map (69632B): staging W1 [0,49152) then W2 [0,16384); compute
// Ein0 [0,25600) | Ein1 [25600,51200) | Eh [51200,68608) |
// sDest0/1 [68608,69120) | sEid0/1 [69120,69632). Eout = Ecur's region.
#define LOAD_ROWS(sv, dv, ee) do {                                        \
    cf32x4* ps_ = (cf32x4*)(x  + (size_t)(sv)*64 + p*16);                 \
    cf32x4* pd_ = (cf32x4*)(x  + (size_t)(dv)*64 + p*16);                 \
    cf32x4* pe_ = (cf32x4*)(ea + (size_t)(ee)*64 + p*16);                 \
    L[0]=ps_[0]; L[1]=ps_[1]; L[2]=ps_[2];  L[3]=ps_[3];                  \
    L[4]=pd_[0]; L[5]=pd_[1]; L[6]=pd_[2];  L[7]=pd_[3];                  \
    L[8]=pe_[0]; L[9]=pe_[1]; L[10]=pe_[2]; L[11]=pe_[3];                 \
  } while (0)

#define WRITE_EIN(buf) do {                                               \
    short* stg_ = (buf) + el*SEI + p*16;                                  \
    ((s16x8*)stg_)[0]       = cvt8(L[0], L[1]);                           \
    ((s16x8*)stg_)[1]       = cvt8(L[2], L[3]);                           \
    ((s16x8*)(stg_+64))[0]  = cvt8(L[4], L[5]);                           \
    ((s16x8*)(stg_+64))[1]  = cvt8(L[6], L[7]);                           \
    ((s16x8*)(stg_+128))[0] = cvt8(L[8], L[9]);                           \
    ((s16x8*)(stg_+128))[1] = cvt8(L[10], L[11]);                         \
  } while (0)

__global__ __launch_bounds__(256, 2)
void edge_kernel(const float* __restrict__ x, const int* __restrict__ eidx,
                 const float* __restrict__ ea, const int* __restrict__ elist,
                 const float* __restrict__ We1, const float* __restrict__ be1,
                 const float* __restrict__ We2, const float* __restrict__ be2,
                 float* __restrict__ edge_out, float* __restrict__ agg)
{
  __shared__ __align__(16) char smem[69632];
  short* sEin0 = (short*)smem;
  short* sEin1 = (short*)(smem + 25600);
  short* sEh   = (short*)(smem + 51200);
  int* sDest0  = (int*)(smem + 68608);
  int* sDest1  = (int*)(smem + 68864);
  int* sEid0   = (int*)(smem + 69120);
  int* sEid1   = (int*)(smem + 69376);

  const int t = threadIdx.x;
  const int wv = t >> 6, lane = t & 63;
  const int r = lane & 15, g = lane >> 4;

  s16x8 w1f[2][6], w2f[4];
  f32x4 b1r[2], b2r;
  load_wfrags_lds(We1, We2, be1, be2, (short*)smem, t, wv, r, g,
                  w1f, w2f, b1r, &b2r);

  const int el = t >> 2, p = t & 3;
  const int nT = NE / 64;                    // 10000
  const int S = (int)gridDim.x;
  const f32x4 zero = {0.f, 0.f, 0.f, 0.f};

  f32x4 L[12];
  int eW = 0, dW = 0;                        // ids of tile T+1 (stage-write)
  int eI = 0, sI = 0, dI = 0;                // ids of tile T+2 (row loads)
  int tile = blockIdx.x;

  if (tile < nT) {                           // prologue: tile T0 fully staged
    int e0 = elist[(tile << 6) + el];
    int s0 = eidx[e0], d0 = eidx[NE + e0];
    LOAD_ROWS(s0, d0, e0);
    WRITE_EIN(sEin0);
    if (p == 0) { sDest0[el] = d0; sEid0[el] = e0; }
    const int t1 = tile + S;
    if (t1 < nT) {
      eW = elist[(t1 << 6) + el];
      int sv = eidx[eW]; dW = eidx[NE + eW];
      LOAD_ROWS(sv, dW, eW);
    }
    const int t2 = tile + 2 * S;
    if (t2 < nT) {
      eI = elist[(t2 << 6) + el];
      sI = eidx[eI]; dI = eidx[NE + eI];
    }
  }
  __syncthreads();

  int cur = 0;
  while (tile < nT) {
    const short* Ecur = cur ? sEin1 : sEin0;
    short* Enxt = cur ? sEin0 : sEin1;
    float* EoutC = (float*)(cur ? (smem + 25600) : smem);
    const int* sDestC = cur ? sDest1 : sDest0;
    const int* sEidC  = cur ? sEid1  : sEid0;
    int* sDestN = cur ? sDest0 : sDest1;
    int* sEidN  = cur ? sEid0  : sEid1;

    const int tW = tile + S, tI = tile + 2 * S, tX = tile + 3 * S;
    if (tW < nT) {                           // stage T+1 (regs from last iter)
      WRITE_EIN(Enxt);
      if (p == 0) { sDestN[el] = dW; sEidN[el] = eW; }
    }
    if (tI < nT) { LOAD_ROWS(sI, dI, eI); eW = eI; dW = dI; }
    if (tX < nT) {
      eI = elist[(tX << 6) + el];
      sI = eidx[eI]; dI = eidx[NE + eI];
    }

    // ---- layer 1: 64 edges x 32 h per wave ----
    f32x4 acc1[2][4];
    #pragma unroll
    for (int nn = 0; nn < 2; ++nn)
      #pragma unroll
      for (int j = 0; j < 4; ++j) acc1[nn][j] = zero;
    #pragma unroll
    for (int kk = 0; kk < 6; ++kk) {
      #pragma unroll
      for (int j = 0; j < 4; ++j) {
        s16x8 ef = *(const s16x8*)&Ecur[(j*16 + r)*SEI + kk*32 + g*8];
        acc1[0][j] = __builtin_amdgcn_mfma_f32_16x16x32_bf16(w1f[0][kk], ef, acc1[0][j], 0, 0, 0);
        acc1[1][j] = __builtin_amdgcn_mfma_f32_16x16x32_bf16(w1f[1][kk], ef, acc1[1][j], 0, 0, 0);
      }
    }
    #pragma unroll
    for (int nn = 0; nn < 2; ++nn)
      #pragma unroll
      for (int j = 0; j < 4; ++j) {
        s16x4 pk;
        #pragma unroll
        for (int q = 0; q < 4; ++q) {
          float v = acc1[nn][j][q] + b1r[nn][q];
          pk[q] = f2bf(v > 0.f ? v : 0.f);
        }
        *(s16x4*)&sEh[(j*16 + r)*SEH + (wv*2+nn)*16 + g*4] = pk;
      }
    __syncthreads();                         // bar A: Eh ready, Ein reads done

    // ---- layer 2 + scattered edge_out store + Eout into Ecur region ----
    #pragma unroll
    for (int j = 0; j < 4; ++j) {
      f32x4 a2 = zero;
      #pragma unroll
      for (int kk = 0; kk < 4; ++kk) {
        s16x8 hf = *(const s16x8*)&sEh[(j*16 + r)*SEH + kk*32 + g*8];
        a2 = __builtin_amdgcn_mfma_f32_16x16x32_bf16(w2f[kk], hf, a2, 0, 0, 0);
      }
      a2 += b2r;
      const int eg = sEidC[j*16 + r];
      *(f32x4*)&edge_out[(size_t)eg*64 + wv*16 + g*4] = a2;
      *(f32x4*)&EoutC[(j*16 + r)*SEO + wv*16 + g*4] = a2;
    }
    __syncthreads();                         // bar C: Eout complete

    // ---- segmented reduce: wave wv owns sorted edges wv*16..+15 ----
    {
      const int row0 = wv * 16;
      float acc = EoutC[row0*SEO + lane];
      int dcur = sDestC[row0];
      #pragma unroll
      for (int k = 1; k < 16; ++k) {
        const int dn = sDestC[row0 + k];     // wave-uniform
        const float v = EoutC[(row0 + k)*SEO + lane];
        if (dn != dcur) {
          unsafeAtomicAdd(&agg[(size_t)dcur*64 + lane], acc);
          acc = v; dcur = dn;
        } else {
          acc += v;
        }
      }
      unsafeAtomicAdd(&agg[(size_t)dcur*64 + lane], acc);
    }
    __syncthreads();                         // bar D: Eout consumed
    cur ^= 1;
    tile = tW;
  }
}

// ---------------- node model ----------------
__global__ __launch_bounds__(256, 2)
void node_kernel(const float* __restrict__ x, const float* agg,
                 const float* __restrict__ f,
                 const float* __restrict__ Wn1, const float* __restrict__ bn1,
                 const float* __restrict__ Wn2, const float* __restrict__ bn2,
                 float* x_out)
{
  __shared__ __align__(16) char smem[49152];
  short* sEin = (short*)smem;
  short* sEh  = (short*)(smem + 25600);

  const int t = threadIdx.x;
  const int wv = t >> 6, lane = t & 63;
  const int r = lane & 15, g = lane >> 4;

  s16x8 w1f[2][6], w2f[4];
  f32x4 b1r[2], b2r;
  load_wfrags_lds(Wn1, Wn2, bn1, bn2, (short*)smem, t, wv, r, g,
                  w1f, w2f, b1r, &b2r);

  const int el = t >> 2, p = t & 3;
  const f32x4 zero = {0.f, 0.f, 0.f, 0.f};
  const int nT = (NN + 63) / 64;             // 313

  for (int tile = blockIdx.x; tile < nT; tile += (int)gridDim.x) {
    const int base = tile << 6;
    const int i = base + el;

    f32x4 L[12];
    if (i < NN) {
      cf32x4* ps_ = (cf32x4*)(x   + (size_t)i*64 + p*16);
      cf32x4* pa_ = (cf32x4*)(agg + (size_t)i*64 + p*16);
      cf32x4* pf_ = (cf32x4*)(f   + (size_t)i*64 + p*16);
      L[0]=ps_[0]; L[1]=ps_[1]; L[2]=ps_[2];  L[3]=ps_[3];
      L[4]=pa_[0]; L[5]=pa_[1]; L[6]=pa_[2];  L[7]=pa_[3];
      L[8]=pf_[0]; L[9]=pf_[1]; L[10]=pf_[2]; L[11]=pf_[3];
    } else {
      #pragma unroll
      for (int q = 0; q < 12; ++q) L[q] = zero;
    }
    WRITE_EIN(sEin);
    __syncthreads();

    f32x4 acc1[2][4];
    #pragma unroll
    for (int nn = 0; nn < 2; ++nn)
      #pragma unroll
      for (int j = 0; j < 4; ++j) acc1[nn][j] = zero;
    #pragma unroll
    for (int kk = 0; kk < 6; ++kk) {
      #pragma unroll
      for (int j = 0; j < 4; ++j) {
        s16x8 ef = *(const s16x8*)&sEin[(j*16 + r)*SEI + kk*32 + g*8];
        acc1[0][j] = __builtin_amdgcn_mfma_f32_16x16x32_bf16(w1f[0][kk], ef, acc1[0][j], 0, 0, 0);
        acc1[1][j] = __builtin_amdgcn_mfma_f32_16x16x32_bf16(w1f[1][kk], ef, acc1[1][j], 0, 0, 0);
      }
    }
    #pragma unroll
    for (int nn = 0; nn < 2; ++nn)
      #pragma unroll
      for (int j = 0; j < 4; ++j) {
        s16x4 pk;
        #pragma unroll
        for (int q = 0; q < 4; ++q) {
          float v = acc1[nn][j][q] + b1r[nn][q];
          pk[q] = f2bf(v > 0.f ? v : 0.f);
        }
        *(s16x4*)&sEh[(j*16 + r)*SEH + (wv*2+nn)*16 + g*4] = pk;
      }
    __syncthreads();

    #pragma unroll
    for (int j = 0; j < 4; ++j) {
      f32x4 a2 = zero;
      #pragma unroll
      for (int kk = 0; kk < 4; ++kk) {
        s16x8 hf = *(const s16x8*)&sEh[(j*16 + r)*SEH + kk*32 + g*8];
        a2 = __builtin_amdgcn_mfma_f32_16x16x32_bf16(w2f[kk], hf, a2, 0, 0, 0);
      }
      const int row = base + j*16 + r;
      if (row < NN) {
        f32x4 v = a2 + b2r;
        *(f32x4*)&x_out[(size_t)row*64 + wv*16 + g*4] = v;
      }
    }
    __syncthreads();
  }
}

extern "C" void kernel_launch(void* const* d_in, const int* in_sizes, int n_in,
                              void* d_out, int out_size, void* d_ws, size_t ws_size,
                              hipStream_t stream) {
  const float* x   = (const float*)d_in[0];
  const int*   ei  = (const int*)d_in[1];
  const float* ea  = (const float*)d_in[2];
  const float* f   = (const float*)d_in[3];
  const float* We1 = (const float*)d_in[4];
  const float* be1 = (const float*)d_in[5];
  const float* We2 = (const float*)d_in[6];
  const float* be2 = (const float*)d_in[7];
  const float* Wn1 = (const float*)d_in[8];
  const float* bn1 = (const float*)d_in[9];
  const float* Wn2 = (const float*)d_in[10];
  const float* bn2 = (const float*)d_in[11];

  float* x_out    = (float*)d_out;                    // [20000*64] — doubles as agg
  float* edge_out = x_out + (size_t)NN * 64;          // [640000*64]

  // CSR scratch in d_ws: cursor[NN] | offs[NN+1] | elist[NE]  (~2.7 MB)
  int* cursor = (int*)d_ws;
  int* offs   = cursor + NN;
  int* elist  = offs + NN + 8;

  hipMemsetAsync(cursor, 0, NN * sizeof(int), stream);
  count_kernel<<<625, 256, 0, stream>>>(ei, cursor, x_out);  // also zeros agg
  scan_kernel<<<1, 1024, 0, stream>>>(cursor, offs);
  scatter_kernel<<<625, 256, 0, stream>>>(ei, cursor, elist);
  edge_kernel<<<512, 256, 0, stream>>>(x, ei, ea, elist, We1, be1, We2, be2,
                                       edge_out, x_out);
  node_kernel<<<105, 256, 0, stream>>>(x, x_out, f, Wn1, bn1, Wn2, bn2, x_out);
}